// Round 7
// baseline (238.349 us; speedup 1.0000x reference)
//
#include <hip/hip_runtime.h>

constexpr int NNODES = 50000;
constexpr int NEDGES = 800000;
constexpr int CAP = 64;   // bucket capacity; deg ~ Poisson(16), P(deg>=64) ~ 1e-19

constexpr int NPART = 8;
constexpr int PSIZE = NNODES / NPART;   // 6250
constexpr int FCH = 1024;               // edges scanned per fill block
constexpr int QCAP = 320;               // matches/block: mean 128, sd ~10.6

constexpr int CHUNKS = (NEDGES + FCH - 1) / FCH;   // 782
constexpr int TILE_ITEMS = (NNODES + 63) / 64;     // 782 (== CHUNKS, 9-way interleave)
constexpr int PACK_TOT = 43008;
constexpr int PREP_ITEMS = NNODES;                 // covers packing (43008) + cursor zero
constexpr int AGG_CHUNK2 = 391;                    // slice-agg: 391*2 = 782 node-chunks

typedef __attribute__((ext_vector_type(8))) short short8;    // 8 bf16 (4 VGPRs)
typedef __attribute__((ext_vector_type(8))) unsigned short ushort8;
typedef __attribute__((ext_vector_type(4))) float f32x4;

__device__ __forceinline__ unsigned short f2b(float f) {   // fp32 -> bf16 RTN-even
    unsigned int u = __float_as_uint(f);
    u += 0x7FFFu + ((u >> 16) & 1u);
    return (unsigned short)(u >> 16);
}
__device__ __forceinline__ float b2f(unsigned short u) {   // exact
    return __uint_as_float(((unsigned int)u) << 16);
}
// packed edge record: low16 = src node id, high16 = bf16 bits of val
__device__ __forceinline__ float recval(unsigned int rec) {
    return __uint_as_float(rec & 0xFFFF0000u);
}

// ---------------------------------------------------------------------------
// Pack W[K][N] (fp32) -> MFMA B-fragment order (bf16).
// ---------------------------------------------------------------------------
template <int N, int K>
__device__ __forceinline__ void pack_one(int idx, const float* __restrict__ W,
                                         unsigned short* __restrict__ Wp) {
    constexpr int KS = K / 32;
    int j = idx & 7;
    int lane = (idx >> 3) & 63;
    int t = idx >> 9;
    int nt = t / KS, ks = t % KS;
    int n = nt * 16 + (lane & 15);
    int k = ks * 32 + (lane >> 4) * 8 + j;
    Wp[idx] = f2b(W[(size_t)k * N + n]);
}

// prep = weight pack + cursor zero (folds the old memset dispatch in).
__global__ __launch_bounds__(256) void prep_kernel(
        const float* __restrict__ W1, const float* __restrict__ W2,
        const float* __restrict__ W3, const float* __restrict__ W4,
        unsigned short* __restrict__ Wp1, unsigned short* __restrict__ Wp2,
        unsigned short* __restrict__ Wp3, unsigned short* __restrict__ Wp4,
        int* __restrict__ cursor) {
    int p = blockIdx.x * 256 + threadIdx.x;
    if (p < NNODES) cursor[p] = 0;
    if (p < 16384) pack_one<128, 128>(p, W1, Wp1);
    else if (p < 32768) pack_one<128, 128>(p - 16384, W2, Wp2);
    else if (p < 40960) pack_one<64, 128>(p - 32768, W3, Wp3);
    else if (p < 43008) pack_one<32, 64>(p - 40960, W4, Wp4);
}

// ---------------------------------------------------------------------------
// MFMA bf16 GEMM tile (64 rows x full N).
// AMODE: 0 = A fp32 row-major; 1 = A bf16 slice-blocked [K/32][NNODES][32].
// CSLICE: C written slice-blocked [N/32][NNODES][32] (else row-major [N]).
// Slice-blocked A-read is 16 consecutive rows x 64B = 1KB/wave, coalesced.
// ---------------------------------------------------------------------------
template <int N, int K, int AMODE, bool CSLICE>
__device__ __forceinline__ void gemm_item(int t, const void* __restrict__ Hv,
                                          const unsigned short* __restrict__ Wp,
                                          unsigned short* __restrict__ Sb) {
    constexpr int NT = N / 16, KS = K / 32;
    const int lane = threadIdx.x & 63;
    const int wave = threadIdx.x >> 6;
    const int waveRow = t * 64 + wave * 16;
    const int m = lane & 15, quad = lane >> 4;
    int arow = waveRow + m;
    if (arow >= NNODES) arow = NNODES - 1;      // clamp; stores are guarded

    f32x4 acc[NT];
#pragma unroll
    for (int nt = 0; nt < NT; ++nt) acc[nt] = (f32x4){0.f, 0.f, 0.f, 0.f};

#pragma unroll
    for (int ks = 0; ks < KS; ++ks) {
        short8 a;
        if (AMODE == 0) {
            const float* hp = (const float*)Hv + (size_t)arow * K + ks * 32 + quad * 8;
            float4 a0 = *reinterpret_cast<const float4*>(hp);
            float4 a1 = *reinterpret_cast<const float4*>(hp + 4);
            a[0] = (short)f2b(a0.x); a[1] = (short)f2b(a0.y);
            a[2] = (short)f2b(a0.z); a[3] = (short)f2b(a0.w);
            a[4] = (short)f2b(a1.x); a[5] = (short)f2b(a1.y);
            a[6] = (short)f2b(a1.z); a[7] = (short)f2b(a1.w);
        } else {
            a = *reinterpret_cast<const short8*>(
                (const unsigned short*)Hv + ((size_t)ks * NNODES + arow) * 32 + quad * 8);
        }
#pragma unroll
        for (int nt = 0; nt < NT; ++nt) {
            short8 b = *reinterpret_cast<const short8*>(Wp + ((nt * KS + ks) * 64 + lane) * 8);
            acc[nt] = __builtin_amdgcn_mfma_f32_16x16x32_bf16(a, b, acc[nt], 0, 0, 0);
        }
    }

#pragma unroll
    for (int reg = 0; reg < 4; ++reg) {
        int grow = waveRow + quad * 4 + reg;
        if (grow < NNODES) {
#pragma unroll
            for (int nt = 0; nt < NT; ++nt) {
                int c = nt * 16 + m;
                if (CSLICE)
                    Sb[((size_t)(c >> 5) * NNODES + grow) * 32 + (c & 31)] = f2b(acc[nt][reg]);
                else
                    Sb[(size_t)grow * N + c] = f2b(acc[nt][reg]);
            }
        }
    }
}

// ---------------------------------------------------------------------------
// INTERLEAVED fill + gemm1 (FROZEN round-3 champion form): blockIdx%9==0 ->
// gemm1 tile (now writing Q slice-blocked); 8 fill blocks per chunk cover the
// 8 XCD-parts; LDS match queue batches the cursor-atomic + bucket-store drain.
// ---------------------------------------------------------------------------
__global__ __launch_bounds__(256) void fill_gemm1_kernel(
        const int* __restrict__ src, const int* __restrict__ dst,
        const float* __restrict__ val, int* __restrict__ cursor,
        unsigned int* __restrict__ buckets,
        const float* __restrict__ x, const unsigned short* __restrict__ Wp1,
        unsigned short* __restrict__ Q) {
    __shared__ unsigned int q_rec[QCAP];
    __shared__ int q_d[QCAP];
    __shared__ int qcount;

    const int g = blockIdx.x / 9;
    const int r = blockIdx.x % 9;
    if (r == 0) {
        gemm_item<128, 128, 0, true>(g, x, Wp1, Q);
        return;
    }

    if (threadIdx.x == 0) qcount = 0;
    __syncthreads();

    const int part = blockIdx.x & 7;       // true XCD heuristic
    const int lo = part * PSIZE, hi = lo + PSIZE;
    const int e0 = g * FCH + threadIdx.x * 4;

    int4 d4 = make_int4(-1, -1, -1, -1);
    int4 s4 = make_int4(0, 0, 0, 0);
    float4 v4 = make_float4(0.f, 0.f, 0.f, 0.f);
    if (e0 + 3 < NEDGES) {
        d4 = *reinterpret_cast<const int4*>(dst + e0);
        s4 = *reinterpret_cast<const int4*>(src + e0);
        v4 = *reinterpret_cast<const float4*>(val + e0);
    } else if (e0 < NEDGES) {
        d4.x = dst[e0]; s4.x = src[e0]; v4.x = val[e0];
        if (e0 + 1 < NEDGES) { d4.y = dst[e0 + 1]; s4.y = src[e0 + 1]; v4.y = val[e0 + 1]; }
        if (e0 + 2 < NEDGES) { d4.z = dst[e0 + 2]; s4.z = src[e0 + 2]; v4.z = val[e0 + 2]; }
    }
    int dd[4] = {d4.x, d4.y, d4.z, d4.w};
    int ss[4] = {s4.x, s4.y, s4.z, s4.w};
    float vv[4] = {v4.x, v4.y, v4.z, v4.w};
#pragma unroll
    for (int i = 0; i < 4; ++i) {
        int d = dd[i];
        if (d >= lo && d < hi) {
            unsigned int rec = (unsigned int)ss[i] | ((unsigned int)f2b(vv[i]) << 16);
            int pos = atomicAdd(&qcount, 1);
            if (pos < QCAP) {
                q_rec[pos] = rec;
                q_d[pos] = d;
            } else {  // overflow fallback (statistically unreachable; correct anyway)
                int p = atomicAdd(&cursor[d], 1);
                if (p < CAP) buckets[(size_t)d * CAP + p] = rec;
            }
        }
    }
    __syncthreads();

    int n = qcount < QCAP ? qcount : QCAP;
    for (int i = threadIdx.x; i < n; i += 256) {
        int d = q_d[i];
        unsigned int rec = q_rec[i];
        int p = atomicAdd(&cursor[d], 1);
        if (p < CAP) buckets[(size_t)d * CAP + p] = rec;
    }
}

// ---------------------------------------------------------------------------
// Pull-aggregation over a bucket-row range: 8-wide software-pipelined gather
// (proven sweet spot: 4-wide=220.6, 8-wide=217.5, 16-wide=228.9, split=233.0).
// ---------------------------------------------------------------------------
template <int NIN>
__device__ __forceinline__ void pull_agg(const unsigned short* __restrict__ Sprev,
                                         const unsigned int* __restrict__ eb,
                                         int cnt, int cg, float* __restrict__ acc) {
    const unsigned short* Sp = Sprev + cg * 8;
    int j = 0;
    for (; j + 8 <= cnt; j += 8) {
        uint4 ea = *reinterpret_cast<const uint4*>(eb + j);
        uint4 ec = *reinterpret_cast<const uint4*>(eb + j + 4);
        const ushort8 m0 = *reinterpret_cast<const ushort8*>(Sp + (ea.x & 0xFFFFu) * (unsigned)NIN);
        const ushort8 m1 = *reinterpret_cast<const ushort8*>(Sp + (ea.y & 0xFFFFu) * (unsigned)NIN);
        const ushort8 m2 = *reinterpret_cast<const ushort8*>(Sp + (ea.z & 0xFFFFu) * (unsigned)NIN);
        const ushort8 m3 = *reinterpret_cast<const ushort8*>(Sp + (ea.w & 0xFFFFu) * (unsigned)NIN);
        const ushort8 m4 = *reinterpret_cast<const ushort8*>(Sp + (ec.x & 0xFFFFu) * (unsigned)NIN);
        const ushort8 m5 = *reinterpret_cast<const ushort8*>(Sp + (ec.y & 0xFFFFu) * (unsigned)NIN);
        const ushort8 m6 = *reinterpret_cast<const ushort8*>(Sp + (ec.z & 0xFFFFu) * (unsigned)NIN);
        const ushort8 m7 = *reinterpret_cast<const ushort8*>(Sp + (ec.w & 0xFFFFu) * (unsigned)NIN);
        float v0 = recval(ea.x), v1 = recval(ea.y), v2 = recval(ea.z), v3 = recval(ea.w);
        float v4 = recval(ec.x), v5 = recval(ec.y), v6 = recval(ec.z), v7 = recval(ec.w);
#pragma unroll
        for (int t = 0; t < 8; ++t) {
            acc[t] = fmaf(b2f(m0[t]), v0, acc[t]);
            acc[t] = fmaf(b2f(m1[t]), v1, acc[t]);
            acc[t] = fmaf(b2f(m2[t]), v2, acc[t]);
            acc[t] = fmaf(b2f(m3[t]), v3, acc[t]);
            acc[t] = fmaf(b2f(m4[t]), v4, acc[t]);
            acc[t] = fmaf(b2f(m5[t]), v5, acc[t]);
            acc[t] = fmaf(b2f(m6[t]), v6, acc[t]);
            acc[t] = fmaf(b2f(m7[t]), v7, acc[t]);
        }
    }
    for (; j + 4 <= cnt; j += 4) {
        uint4 ea = *reinterpret_cast<const uint4*>(eb + j);
        const ushort8 m0 = *reinterpret_cast<const ushort8*>(Sp + (ea.x & 0xFFFFu) * (unsigned)NIN);
        const ushort8 m1 = *reinterpret_cast<const ushort8*>(Sp + (ea.y & 0xFFFFu) * (unsigned)NIN);
        const ushort8 m2 = *reinterpret_cast<const ushort8*>(Sp + (ea.z & 0xFFFFu) * (unsigned)NIN);
        const ushort8 m3 = *reinterpret_cast<const ushort8*>(Sp + (ea.w & 0xFFFFu) * (unsigned)NIN);
        float v0 = recval(ea.x), v1 = recval(ea.y);
        float v2 = recval(ea.z), v3 = recval(ea.w);
#pragma unroll
        for (int t = 0; t < 8; ++t) {
            acc[t] = fmaf(b2f(m0[t]), v0, acc[t]);
            acc[t] = fmaf(b2f(m1[t]), v1, acc[t]);
            acc[t] = fmaf(b2f(m2[t]), v2, acc[t]);
            acc[t] = fmaf(b2f(m3[t]), v3, acc[t]);
        }
    }
    for (; j < cnt; ++j) {
        unsigned int r = eb[j];
        float v = recval(r);
        const ushort8 mr = *reinterpret_cast<const ushort8*>(Sp + (r & 0xFFFFu) * (unsigned)NIN);
#pragma unroll
        for (int t = 0; t < 8; ++t) acc[t] = fmaf(b2f(mr[t]), v, acc[t]);
    }
}

// ---------------------------------------------------------------------------
// SLICE-SPLIT aggregation for 128-ch layers: input slice-blocked
// [4][NNODES][32ch]. Block handles one 32-ch slice x 64 nodes; slice =
// (blockIdx%8)&3 so each XCD (blockIdx%8) touches ONE 3.2 MB slice panel ->
// L2-resident gathers. Two XCDs split each slice's node range (sub-chunking).
// Per-thread loop identical to the champion (8ch acc, 8-wide pull): only the
// gather footprint per XCD changes. Output: relu(agg+b), slice-blocked.
// ---------------------------------------------------------------------------
__global__ __launch_bounds__(256) void agg_slice_kernel(
        const unsigned short* __restrict__ Sprev, const unsigned int* __restrict__ buckets,
        const int* __restrict__ counts, const float* __restrict__ bias,
        unsigned short* __restrict__ Hout) {
    const int xcd = blockIdx.x & 7;
    const int ss = xcd & 3;                 // slice 0..3 (2 XCDs per slice)
    const int sub = xcd >> 2;               // 0/1: which half of the chunks
    const int chunk = (blockIdx.x >> 3) * 2 + sub;   // 0..781
    const int nl = threadIdx.x >> 2;        // node within chunk (0..63)
    const int cg = threadIdx.x & 3;         // 8-ch group within slice
    const int node = chunk * 64 + nl;
    if (node >= NNODES) return;

    float acc[8];
#pragma unroll
    for (int t = 0; t < 8; ++t) acc[t] = bias[ss * 32 + cg * 8 + t];
    int cnt = counts[node];
    if (cnt > CAP) cnt = CAP;
    pull_agg<32>(Sprev + (size_t)ss * NNODES * 32, buckets + (size_t)node * CAP,
                 cnt, cg, acc);

    ushort8 o;
#pragma unroll
    for (int t = 0; t < 8; ++t) o[t] = f2b(fmaxf(acc[t], 0.f));
    *reinterpret_cast<ushort8*>(Hout + ((size_t)ss * NNODES + node) * 32 + cg * 8) = o;
}

// ---------------------------------------------------------------------------
// Standalone GEMM on slice-blocked bf16 A (K=128): 64-row tiles, 4 waves.
// ---------------------------------------------------------------------------
template <int N, bool CSLICE>
__global__ __launch_bounds__(256) void gemm_sb_kernel(
        const unsigned short* __restrict__ A, const unsigned short* __restrict__ Wp,
        unsigned short* __restrict__ C) {
    gemm_item<N, 128, 1, CSLICE>(blockIdx.x, A, Wp, C);
}

// ---------------------------------------------------------------------------
// FUSED agg3 + gemm4 (champion round-3 form): NIN=64 row-major input (6.4 MB,
// ~L2-resident), 8 threads/node, 32 nodes/block, htile in LDS, 4 waves MFMA.
// ---------------------------------------------------------------------------
__global__ __launch_bounds__(256) void agg_gemm64_kernel(
        const unsigned short* __restrict__ Sprev, const unsigned int* __restrict__ buckets,
        const int* __restrict__ counts, const float* __restrict__ bias,
        const unsigned short* __restrict__ Wp, unsigned short* __restrict__ Snext) {
    constexpr int NIN = 64, NOUT = 32;
    constexpr int NCH = NIN / 8;        // 8 threads per node
    constexpr int R = 256 / NCH;        // 32 nodes per block
    constexpr int LROW = NIN + 8;
    constexpr int KS = NIN / 32;
    constexpr int NT = NOUT / 16;
    constexpr int RT = R / 16;
    constexpr int TILES = RT * NT;
    __shared__ unsigned short htile[R * LROW];

    const int nodeBase = blockIdx.x * R;

    {
        int nl = threadIdx.x / NCH;
        int cg = threadIdx.x % NCH;
        int node = nodeBase + nl;
        float acc[8];
        if (node < NNODES) {
#pragma unroll
            for (int t = 0; t < 8; ++t) acc[t] = bias[cg * 8 + t];
            int cnt = counts[node];
            if (cnt > CAP) cnt = CAP;
            pull_agg<NIN>(Sprev, buckets + (size_t)node * CAP, cnt, cg, acc);
        } else {
#pragma unroll
            for (int t = 0; t < 8; ++t) acc[t] = 0.f;
        }
        ushort8 o;
#pragma unroll
        for (int t = 0; t < 8; ++t) o[t] = f2b(fmaxf(acc[t], 0.f));
        *reinterpret_cast<ushort8*>(&htile[nl * LROW + cg * 8]) = o;
    }
    __syncthreads();

    {
        const int lane = threadIdx.x & 63, wave = threadIdx.x >> 6;
        const int m = lane & 15, quad = lane >> 4;
        for (int t = wave; t < TILES; t += 4) {
            int rt = t / NT, nt = t % NT;
            f32x4 acc = (f32x4){0.f, 0.f, 0.f, 0.f};
#pragma unroll
            for (int ks = 0; ks < KS; ++ks) {
                short8 a = *reinterpret_cast<const short8*>(
                    &htile[(rt * 16 + m) * LROW + ks * 32 + quad * 8]);
                short8 b = *reinterpret_cast<const short8*>(Wp + ((nt * KS + ks) * 64 + lane) * 8);
                acc = __builtin_amdgcn_mfma_f32_16x16x32_bf16(a, b, acc, 0, 0, 0);
            }
#pragma unroll
            for (int reg = 0; reg < 4; ++reg) {
                int grow = nodeBase + rt * 16 + quad * 4 + reg;
                if (grow < NNODES)
                    Snext[(size_t)grow * NOUT + nt * 16 + m] = f2b(acc[reg]);
            }
        }
    }
}

// ---------------------------------------------------------------------------
// Final pull aggregation (layer 4, champion form): 32-ch row-major input
// (3.2 MB, L2-resident), 4 threads/node, fp32 output.
// ---------------------------------------------------------------------------
__global__ __launch_bounds__(256) void agg_out_kernel(const unsigned short* __restrict__ Sb,
        const unsigned int* __restrict__ buckets, const int* __restrict__ counts,
        const float* __restrict__ bias, float* __restrict__ outp) {
    constexpr int N = 32;
    int node = blockIdx.x * 64 + threadIdx.x / 4;
    int cg = threadIdx.x % 4;
    if (node >= NNODES) return;
    float acc[8];
#pragma unroll
    for (int t = 0; t < 8; ++t) acc[t] = bias[cg * 8 + t];

    int cnt = counts[node];
    if (cnt > CAP) cnt = CAP;
    pull_agg<N>(Sb, buckets + (size_t)node * CAP, cnt, cg, acc);

    float* op = outp + (size_t)node * N + cg * 8;
    *reinterpret_cast<float4*>(op) = make_float4(acc[0], acc[1], acc[2], acc[3]);
    *reinterpret_cast<float4*>(op + 4) = make_float4(acc[4], acc[5], acc[6], acc[7]);
}

extern "C" void kernel_launch(void* const* d_in, const int* in_sizes, int n_in,
                              void* d_out, int out_size, void* d_ws, size_t ws_size,
                              hipStream_t stream) {
    const float* x   = (const float*)d_in[0];
    const int*   src = (const int*)d_in[1];
    const int*   dst = (const int*)d_in[2];
    const float* val = (const float*)d_in[3];
    const float* W1  = (const float*)d_in[4];
    const float* b1  = (const float*)d_in[5];
    const float* W2  = (const float*)d_in[6];
    const float* b2  = (const float*)d_in[7];
    const float* W3  = (const float*)d_in[8];
    const float* b3  = (const float*)d_in[9];
    const float* W4  = (const float*)d_in[10];
    const float* b4  = (const float*)d_in[11];
    float* out = (float*)d_out;

    unsigned short* B1 = (unsigned short*)d_ws;           // bf16 50000x128 (ping)
    unsigned short* B2 = B1 + (size_t)NNODES * 128;       // bf16 50000x128 (pong)
    unsigned int* buckets = (unsigned int*)(B2 + (size_t)NNODES * 128);  // 12.8 MB
    unsigned short* Wp1 = (unsigned short*)(buckets + (size_t)NNODES * CAP);
    unsigned short* Wp2 = Wp1 + 128 * 128;
    unsigned short* Wp3 = Wp2 + 128 * 128;
    unsigned short* Wp4 = Wp3 + 128 * 64;
    int* cursor = (int*)(Wp4 + 64 * 32);                  // NNODES (counter, then degree)

    const dim3 blk(256);

    // weight pack + cursor zeroing (no memset dispatch)
    prep_kernel<<<(PREP_ITEMS + 255) / 256, blk, 0, stream>>>(
        W1, W2, W3, W4, Wp1, Wp2, Wp3, Wp4, cursor);
    // interleaved fill + gemm1 (9-way); Q = bf16(x@W1) slice-blocked -> B1
    fill_gemm1_kernel<<<CHUNKS * 9, blk, 0, stream>>>(
        src, dst, val, cursor, buckets, x, Wp1, B1);
    // agg1 (slice-split, XCD-pinned): H1 = relu(agg(Q)+b1) slice-blocked -> B2
    agg_slice_kernel<<<AGG_CHUNK2 * 8, blk, 0, stream>>>(
        B1, buckets, cursor, b1, B2);
    // gemm2: P = H1 @ W2, slice-blocked -> B1
    gemm_sb_kernel<128, true><<<TILE_ITEMS, blk, 0, stream>>>(B2, Wp2, B1);
    // agg2 (slice-split): H2 = relu(agg(P)+b2) slice-blocked -> B2
    agg_slice_kernel<<<AGG_CHUNK2 * 8, blk, 0, stream>>>(
        B1, buckets, cursor, b2, B2);
    // gemm3: Q2 = H2 @ W3, row-major 64ch -> B1
    gemm_sb_kernel<64, false><<<TILE_ITEMS, blk, 0, stream>>>(B2, Wp3, B1);
    // agg3 + gemm4 fused: P2 = (relu(agg(Q2)+b3)) @ W4, row-major 32ch -> B2
    agg_gemm64_kernel<<<(NNODES + 31) / 32, blk, 0, stream>>>(
        B1, buckets, cursor, b3, Wp4, B2);
    // agg4 : out = agg(P2) + b4 (fp32)
    agg_out_kernel<<<(NNODES + 63) / 64, blk, 0, stream>>>(B2, buckets, cursor, b4, out);
}

// Round 8
// 216.992 us; speedup vs baseline: 1.0984x; 1.0984x over previous
//
#include <hip/hip_runtime.h>

constexpr int NNODES = 50000;
constexpr int NEDGES = 800000;
constexpr int CAP = 64;   // bucket capacity; deg ~ Poisson(16), P(deg>=64) ~ 1e-19

constexpr int NPART = 8;
constexpr int PSIZE = NNODES / NPART;   // 6250
constexpr int FCH = 1024;               // edges scanned per fill block
constexpr int QCAP = 320;               // matches/block: mean 128, sd ~10.6

constexpr int CHUNKS = (NEDGES + FCH - 1) / FCH;   // 782
constexpr int TILE_ITEMS = (NNODES + 63) / 64;     // 782 (== CHUNKS, 9-way interleave)
constexpr int PACK_TOT = 43008;
constexpr int PREP_ITEMS = NNODES;                 // covers packing (43008) + cursor zero

typedef __attribute__((ext_vector_type(8))) short short8;    // 8 bf16 (4 VGPRs)
typedef __attribute__((ext_vector_type(8))) unsigned short ushort8;
typedef __attribute__((ext_vector_type(4))) float f32x4;

__device__ __forceinline__ unsigned short f2b(float f) {   // fp32 -> bf16 RTN-even
    unsigned int u = __float_as_uint(f);
    u += 0x7FFFu + ((u >> 16) & 1u);
    return (unsigned short)(u >> 16);
}
__device__ __forceinline__ float b2f(unsigned short u) {   // exact
    return __uint_as_float(((unsigned int)u) << 16);
}
// packed edge record: low16 = src node id, high16 = bf16 bits of val
__device__ __forceinline__ float recval(unsigned int rec) {
    return __uint_as_float(rec & 0xFFFF0000u);
}

// ---------------------------------------------------------------------------
// Pack W[K][N] (fp32) -> MFMA B-fragment order (bf16).
// ---------------------------------------------------------------------------
template <int N, int K>
__device__ __forceinline__ void pack_one(int idx, const float* __restrict__ W,
                                         unsigned short* __restrict__ Wp) {
    constexpr int KS = K / 32;
    int j = idx & 7;
    int lane = (idx >> 3) & 63;
    int t = idx >> 9;
    int nt = t / KS, ks = t % KS;
    int n = nt * 16 + (lane & 15);
    int k = ks * 32 + (lane >> 4) * 8 + j;
    Wp[idx] = f2b(W[(size_t)k * N + n]);
}

// prep = weight pack + cursor zero (folds the old memset dispatch in).
__global__ __launch_bounds__(256) void prep_kernel(
        const float* __restrict__ W1, const float* __restrict__ W2,
        const float* __restrict__ W3, const float* __restrict__ W4,
        unsigned short* __restrict__ Wp1, unsigned short* __restrict__ Wp2,
        unsigned short* __restrict__ Wp3, unsigned short* __restrict__ Wp4,
        int* __restrict__ cursor) {
    int p = blockIdx.x * 256 + threadIdx.x;
    if (p < NNODES) cursor[p] = 0;
    if (p < 16384) pack_one<128, 128>(p, W1, Wp1);
    else if (p < 32768) pack_one<128, 128>(p - 16384, W2, Wp2);
    else if (p < 40960) pack_one<64, 128>(p - 32768, W3, Wp3);
    else if (p < 43008) pack_one<32, 64>(p - 40960, W4, Wp4);
}

// ---------------------------------------------------------------------------
// MFMA bf16 GEMM tile (64 rows x full N). Fragment maps per learn_hip m89/m120.
// ---------------------------------------------------------------------------
template <int N, int K, bool AF32>
__device__ __forceinline__ void gemm_item(int t, const void* __restrict__ Hv,
                                          const unsigned short* __restrict__ Wp,
                                          unsigned short* __restrict__ Sb) {
    constexpr int NT = N / 16, KS = K / 32;
    const int lane = threadIdx.x & 63;
    const int wave = threadIdx.x >> 6;
    const int waveRow = t * 64 + wave * 16;
    const int m = lane & 15, quad = lane >> 4;
    int arow = waveRow + m;
    if (arow >= NNODES) arow = NNODES - 1;      // clamp; stores are guarded

    f32x4 acc[NT];
#pragma unroll
    for (int nt = 0; nt < NT; ++nt) acc[nt] = (f32x4){0.f, 0.f, 0.f, 0.f};

#pragma unroll
    for (int ks = 0; ks < KS; ++ks) {
        short8 a;
        if (AF32) {
            const float* hp = (const float*)Hv + (size_t)arow * K + ks * 32 + quad * 8;
            float4 a0 = *reinterpret_cast<const float4*>(hp);
            float4 a1 = *reinterpret_cast<const float4*>(hp + 4);
            a[0] = (short)f2b(a0.x); a[1] = (short)f2b(a0.y);
            a[2] = (short)f2b(a0.z); a[3] = (short)f2b(a0.w);
            a[4] = (short)f2b(a1.x); a[5] = (short)f2b(a1.y);
            a[6] = (short)f2b(a1.z); a[7] = (short)f2b(a1.w);
        } else {
            a = *reinterpret_cast<const short8*>(
                (const unsigned short*)Hv + (size_t)arow * K + ks * 32 + quad * 8);
        }
#pragma unroll
        for (int nt = 0; nt < NT; ++nt) {
            short8 b = *reinterpret_cast<const short8*>(Wp + ((nt * KS + ks) * 64 + lane) * 8);
            acc[nt] = __builtin_amdgcn_mfma_f32_16x16x32_bf16(a, b, acc[nt], 0, 0, 0);
        }
    }

#pragma unroll
    for (int reg = 0; reg < 4; ++reg) {
        int grow = waveRow + quad * 4 + reg;
        if (grow < NNODES) {
#pragma unroll
            for (int nt = 0; nt < NT; ++nt)
                Sb[(size_t)grow * N + nt * 16 + m] = f2b(acc[nt][reg]);
        }
    }
}

// ---------------------------------------------------------------------------
// INTERLEAVED fill + gemm1 (FROZEN round-3 champion form): blockIdx%9==0 ->
// gemm1 tile; 8 fill blocks per chunk cover the 8 XCD-parts; LDS match queue
// batches the cursor-atomic + bucket-store drain.
// Restructures tested and REJECTED: CSR+hist (r1, +44), partition-router
// (r2, +18), slice-owner no-atomic fill (r4, +619).
// ---------------------------------------------------------------------------
__global__ __launch_bounds__(256) void fill_gemm1_kernel(
        const int* __restrict__ src, const int* __restrict__ dst,
        const float* __restrict__ val, int* __restrict__ cursor,
        unsigned int* __restrict__ buckets,
        const float* __restrict__ x, const unsigned short* __restrict__ Wp1,
        unsigned short* __restrict__ Q) {
    __shared__ unsigned int q_rec[QCAP];
    __shared__ int q_d[QCAP];
    __shared__ int qcount;

    const int g = blockIdx.x / 9;
    const int r = blockIdx.x % 9;
    if (r == 0) {
        gemm_item<128, 128, true>(g, x, Wp1, Q);
        return;
    }

    if (threadIdx.x == 0) qcount = 0;
    __syncthreads();

    const int part = blockIdx.x & 7;       // true XCD heuristic
    const int lo = part * PSIZE, hi = lo + PSIZE;
    const int e0 = g * FCH + threadIdx.x * 4;

    int4 d4 = make_int4(-1, -1, -1, -1);
    int4 s4 = make_int4(0, 0, 0, 0);
    float4 v4 = make_float4(0.f, 0.f, 0.f, 0.f);
    if (e0 + 3 < NEDGES) {
        d4 = *reinterpret_cast<const int4*>(dst + e0);
        s4 = *reinterpret_cast<const int4*>(src + e0);
        v4 = *reinterpret_cast<const float4*>(val + e0);
    } else if (e0 < NEDGES) {
        d4.x = dst[e0]; s4.x = src[e0]; v4.x = val[e0];
        if (e0 + 1 < NEDGES) { d4.y = dst[e0 + 1]; s4.y = src[e0 + 1]; v4.y = val[e0 + 1]; }
        if (e0 + 2 < NEDGES) { d4.z = dst[e0 + 2]; s4.z = src[e0 + 2]; v4.z = val[e0 + 2]; }
    }
    int dd[4] = {d4.x, d4.y, d4.z, d4.w};
    int ss[4] = {s4.x, s4.y, s4.z, s4.w};
    float vv[4] = {v4.x, v4.y, v4.z, v4.w};
#pragma unroll
    for (int i = 0; i < 4; ++i) {
        int d = dd[i];
        if (d >= lo && d < hi) {
            unsigned int rec = (unsigned int)ss[i] | ((unsigned int)f2b(vv[i]) << 16);
            int pos = atomicAdd(&qcount, 1);
            if (pos < QCAP) {
                q_rec[pos] = rec;
                q_d[pos] = d;
            } else {  // overflow fallback (statistically unreachable; correct anyway)
                int p = atomicAdd(&cursor[d], 1);
                if (p < CAP) buckets[(size_t)d * CAP + p] = rec;
            }
        }
    }
    __syncthreads();

    int n = qcount < QCAP ? qcount : QCAP;
    for (int i = threadIdx.x; i < n; i += 256) {
        int d = q_d[i];
        unsigned int rec = q_rec[i];
        int p = atomicAdd(&cursor[d], 1);
        if (p < CAP) buckets[(size_t)d * CAP + p] = rec;
    }
}

// ---------------------------------------------------------------------------
// Pull-aggregation over a bucket row: 8-wide software-pipelined gather.
// PROVEN SWEET SPOT: 4-wide=220.6, 8-wide=217.5, 16-wide=228.9 (VGPR/occ
// cliff), edge-split=233.0 (LDS-combine overhead), slice-split=238.3
// (de-fuse + record re-read overhead). Bucket rows 256B-aligned.
// ---------------------------------------------------------------------------
template <int NIN>
__device__ __forceinline__ void pull_agg(const unsigned short* __restrict__ Sprev,
                                         const unsigned int* __restrict__ eb,
                                         int cnt, int cg, float* __restrict__ acc) {
    const unsigned short* Sp = Sprev + cg * 8;
    int j = 0;
    for (; j + 8 <= cnt; j += 8) {
        uint4 ea = *reinterpret_cast<const uint4*>(eb + j);
        uint4 ec = *reinterpret_cast<const uint4*>(eb + j + 4);
        const ushort8 m0 = *reinterpret_cast<const ushort8*>(Sp + (ea.x & 0xFFFFu) * (unsigned)NIN);
        const ushort8 m1 = *reinterpret_cast<const ushort8*>(Sp + (ea.y & 0xFFFFu) * (unsigned)NIN);
        const ushort8 m2 = *reinterpret_cast<const ushort8*>(Sp + (ea.z & 0xFFFFu) * (unsigned)NIN);
        const ushort8 m3 = *reinterpret_cast<const ushort8*>(Sp + (ea.w & 0xFFFFu) * (unsigned)NIN);
        const ushort8 m4 = *reinterpret_cast<const ushort8*>(Sp + (ec.x & 0xFFFFu) * (unsigned)NIN);
        const ushort8 m5 = *reinterpret_cast<const ushort8*>(Sp + (ec.y & 0xFFFFu) * (unsigned)NIN);
        const ushort8 m6 = *reinterpret_cast<const ushort8*>(Sp + (ec.z & 0xFFFFu) * (unsigned)NIN);
        const ushort8 m7 = *reinterpret_cast<const ushort8*>(Sp + (ec.w & 0xFFFFu) * (unsigned)NIN);
        float v0 = recval(ea.x), v1 = recval(ea.y), v2 = recval(ea.z), v3 = recval(ea.w);
        float v4 = recval(ec.x), v5 = recval(ec.y), v6 = recval(ec.z), v7 = recval(ec.w);
#pragma unroll
        for (int t = 0; t < 8; ++t) {
            acc[t] = fmaf(b2f(m0[t]), v0, acc[t]);
            acc[t] = fmaf(b2f(m1[t]), v1, acc[t]);
            acc[t] = fmaf(b2f(m2[t]), v2, acc[t]);
            acc[t] = fmaf(b2f(m3[t]), v3, acc[t]);
            acc[t] = fmaf(b2f(m4[t]), v4, acc[t]);
            acc[t] = fmaf(b2f(m5[t]), v5, acc[t]);
            acc[t] = fmaf(b2f(m6[t]), v6, acc[t]);
            acc[t] = fmaf(b2f(m7[t]), v7, acc[t]);
        }
    }
    for (; j + 4 <= cnt; j += 4) {
        uint4 ea = *reinterpret_cast<const uint4*>(eb + j);
        const ushort8 m0 = *reinterpret_cast<const ushort8*>(Sp + (ea.x & 0xFFFFu) * (unsigned)NIN);
        const ushort8 m1 = *reinterpret_cast<const ushort8*>(Sp + (ea.y & 0xFFFFu) * (unsigned)NIN);
        const ushort8 m2 = *reinterpret_cast<const ushort8*>(Sp + (ea.z & 0xFFFFu) * (unsigned)NIN);
        const ushort8 m3 = *reinterpret_cast<const ushort8*>(Sp + (ea.w & 0xFFFFu) * (unsigned)NIN);
        float v0 = recval(ea.x), v1 = recval(ea.y);
        float v2 = recval(ea.z), v3 = recval(ea.w);
#pragma unroll
        for (int t = 0; t < 8; ++t) {
            acc[t] = fmaf(b2f(m0[t]), v0, acc[t]);
            acc[t] = fmaf(b2f(m1[t]), v1, acc[t]);
            acc[t] = fmaf(b2f(m2[t]), v2, acc[t]);
            acc[t] = fmaf(b2f(m3[t]), v3, acc[t]);
        }
    }
    for (; j < cnt; ++j) {
        unsigned int r = eb[j];
        float v = recval(r);
        const ushort8 mr = *reinterpret_cast<const ushort8*>(Sp + (r & 0xFFFFu) * (unsigned)NIN);
#pragma unroll
        for (int t = 0; t < 8; ++t) acc[t] = fmaf(b2f(mr[t]), v, acc[t]);
    }
}

// ---------------------------------------------------------------------------
// FUSED agg_i + gemm_{i+1} (occupancy-preserving): R = 2048/NIN nodes/block,
// NIN/8 threads per node; relu'd bf16 h-tile in LDS; 4 waves MFMA it.
// ---------------------------------------------------------------------------
template <int NIN, int NOUT>
__global__ __launch_bounds__(256) void agg_gemm_kernel(
        const unsigned short* __restrict__ Sprev, const unsigned int* __restrict__ buckets,
        const int* __restrict__ counts, const float* __restrict__ bias,
        const unsigned short* __restrict__ Wp, unsigned short* __restrict__ Snext) {
    constexpr int NCH = NIN / 8;        // threads per node (16 or 8)
    constexpr int R = 256 / NCH;        // nodes per block (16 or 32)
    constexpr int LROW = NIN + 8;       // LDS row stride (16B-aligned pad)
    constexpr int KS = NIN / 32;
    constexpr int NT = NOUT / 16;
    constexpr int RT = R / 16;
    constexpr int TILES = RT * NT;
    __shared__ unsigned short htile[R * LROW];

    const int nodeBase = blockIdx.x * R;

    // ---- Phase A: pull-agg + bias + relu -> LDS ----
    {
        int nl = threadIdx.x / NCH;
        int cg = threadIdx.x % NCH;
        int node = nodeBase + nl;
        float acc[8];
        if (node < NNODES) {
#pragma unroll
            for (int t = 0; t < 8; ++t) acc[t] = bias[cg * 8 + t];
            int cnt = counts[node];
            if (cnt > CAP) cnt = CAP;
            pull_agg<NIN>(Sprev, buckets + (size_t)node * CAP, cnt, cg, acc);
        } else {
#pragma unroll
            for (int t = 0; t < 8; ++t) acc[t] = 0.f;
        }
        ushort8 o;
#pragma unroll
        for (int t = 0; t < 8; ++t) o[t] = f2b(fmaxf(acc[t], 0.f));
        *reinterpret_cast<ushort8*>(&htile[nl * LROW + cg * 8]) = o;
    }
    __syncthreads();

    // ---- Phase B: R x NOUT MFMA GEMM on the LDS tile ----
    {
        const int lane = threadIdx.x & 63, wave = threadIdx.x >> 6;
        const int m = lane & 15, quad = lane >> 4;
        for (int t = wave; t < TILES; t += 4) {
            int rt = t / NT, nt = t % NT;
            f32x4 acc = (f32x4){0.f, 0.f, 0.f, 0.f};
#pragma unroll
            for (int ks = 0; ks < KS; ++ks) {
                short8 a = *reinterpret_cast<const short8*>(
                    &htile[(rt * 16 + m) * LROW + ks * 32 + quad * 8]);
                short8 b = *reinterpret_cast<const short8*>(Wp + ((nt * KS + ks) * 64 + lane) * 8);
                acc = __builtin_amdgcn_mfma_f32_16x16x32_bf16(a, b, acc, 0, 0, 0);
            }
#pragma unroll
            for (int reg = 0; reg < 4; ++reg) {
                int grow = nodeBase + rt * 16 + quad * 4 + reg;
                if (grow < NNODES)
                    Snext[(size_t)grow * NOUT + nt * 16 + m] = f2b(acc[reg]);
            }
        }
    }
}

// ---------------------------------------------------------------------------
// Final pull aggregation (layer 4): 32-wide, fp32 output to d_out.
// ---------------------------------------------------------------------------
__global__ __launch_bounds__(256) void agg_out_kernel(const unsigned short* __restrict__ Sb,
        const unsigned int* __restrict__ buckets, const int* __restrict__ counts,
        const float* __restrict__ bias, float* __restrict__ outp) {
    constexpr int N = 32;
    int node = blockIdx.x * 64 + threadIdx.x / 4;
    int cg = threadIdx.x % 4;
    if (node >= NNODES) return;
    float acc[8];
#pragma unroll
    for (int t = 0; t < 8; ++t) acc[t] = bias[cg * 8 + t];

    int cnt = counts[node];
    if (cnt > CAP) cnt = CAP;
    pull_agg<N>(Sb, buckets + (size_t)node * CAP, cnt, cg, acc);

    float* op = outp + (size_t)node * N + cg * 8;
    *reinterpret_cast<float4*>(op) = make_float4(acc[0], acc[1], acc[2], acc[3]);
    *reinterpret_cast<float4*>(op + 4) = make_float4(acc[4], acc[5], acc[6], acc[7]);
}

extern "C" void kernel_launch(void* const* d_in, const int* in_sizes, int n_in,
                              void* d_out, int out_size, void* d_ws, size_t ws_size,
                              hipStream_t stream) {
    const float* x   = (const float*)d_in[0];
    const int*   src = (const int*)d_in[1];
    const int*   dst = (const int*)d_in[2];
    const float* val = (const float*)d_in[3];
    const float* W1  = (const float*)d_in[4];
    const float* b1  = (const float*)d_in[5];
    const float* W2  = (const float*)d_in[6];
    const float* b2  = (const float*)d_in[7];
    const float* W3  = (const float*)d_in[8];
    const float* b3  = (const float*)d_in[9];
    const float* W4  = (const float*)d_in[10];
    const float* b4  = (const float*)d_in[11];
    float* out = (float*)d_out;

    unsigned short* P = (unsigned short*)d_ws;            // bf16 50000x128
    unsigned short* Q = P + (size_t)NNODES * 128;         // bf16 50000x128
    unsigned int* buckets = (unsigned int*)(Q + (size_t)NNODES * 128);  // u32 x 50000*64 = 12.8 MB
    unsigned short* Wp1 = (unsigned short*)(buckets + (size_t)NNODES * CAP);
    unsigned short* Wp2 = Wp1 + 128 * 128;
    unsigned short* Wp3 = Wp2 + 128 * 128;
    unsigned short* Wp4 = Wp3 + 128 * 64;
    int* cursor = (int*)(Wp4 + 64 * 32);                  // NNODES (counter, then degree)

    const dim3 blk(256);

    // weight pack + cursor zeroing (no memset dispatch)
    prep_kernel<<<(PREP_ITEMS + 255) / 256, blk, 0, stream>>>(
        W1, W2, W3, W4, Wp1, Wp2, Wp3, Wp4, cursor);
    // interleaved fill + gemm1 (9-way): 782*9 blocks
    fill_gemm1_kernel<<<CHUNKS * 9, blk, 0, stream>>>(
        src, dst, val, cursor, buckets, x, Wp1, Q);
    // agg1 + gemm2 : P = (relu(agg(Q)+b1)) @ W2
    agg_gemm_kernel<128, 128><<<(NNODES + 15) / 16, blk, 0, stream>>>(
        Q, buckets, cursor, b1, Wp2, P);
    // agg2 + gemm3 : Q = (relu(agg(P)+b2)) @ W3
    agg_gemm_kernel<128, 64><<<(NNODES + 15) / 16, blk, 0, stream>>>(
        P, buckets, cursor, b2, Wp3, Q);
    // agg3 + gemm4 : P = (relu(agg(Q)+b3)) @ W4
    agg_gemm_kernel<64, 32><<<(NNODES + 31) / 32, blk, 0, stream>>>(
        Q, buckets, cursor, b3, Wp4, P);
    // agg4 : out = agg(P) + b4 (fp32)
    agg_out_kernel<<<(NNODES + 63) / 64, blk, 0, stream>>>(P, buckets, cursor, b4, out);
}